// Round 5
// baseline (276.890 us; speedup 1.0000x reference)
//
#include <hip/hip_runtime.h>
#include <hip/hip_bf16.h>

#define P_CLS 512
#define D_DIM 2048
#define CAP   32
#define TAU_INV 2.0f

typedef short short8 __attribute__((ext_vector_type(8)));
typedef float f32x4 __attribute__((ext_vector_type(4)));

__device__ __forceinline__ unsigned short f2bf_bits(float x) {
  __hip_bfloat16 b = __float2bfloat16(x);
  unsigned short u;
  __builtin_memcpy(&u, &b, sizeof(u));
  return u;
}

__device__ __forceinline__ float xred_sum(float v) {
#pragma unroll
  for (int o = 1; o < 64; o <<= 1) v += __shfl_xor(v, o, 64);
  return v;
}
__device__ __forceinline__ float xred_max(float v) {
#pragma unroll
  for (int o = 1; o < 64; o <<= 1) v = fmaxf(v, __shfl_xor(v, o, 64));
  return v;
}

__global__ void k_init(int* cnt, float* accs) {
  int t = blockIdx.x * blockDim.x + threadIdx.x;
  if (t < P_CLS) cnt[t] = 0;
  if (t < 8) accs[t] = 0.f;
}

__global__ void k_index(const int* __restrict__ label, int* __restrict__ cnt,
                        int* __restrict__ idx, int n) {
  int i = blockIdx.x * blockDim.x + threadIdx.x;
  if (i < n) {
    int p = label[i];
    int slot = atomicAdd(&cnt[p], 1);
    if (slot < CAP) idx[p * CAP + slot] = i;
  }
}

// R5 pass 1: one wave per row, pure streaming. Load 8 KB coalesced, lane-local
// ssq, shfl reduce, store inv-norm. No barriers, no reuse -> deep TLP (32
// waves/CU x 8 KB in flight). Reads also warm the 256 MB L3 for pass 2.
__global__ __launch_bounds__(256)
void k_norms(const float* __restrict__ f0, const float* __restrict__ f1,
             const float* __restrict__ f2, float* __restrict__ wnorm, int n) {
  int m = blockIdx.y;
  const float* F = (m == 0) ? f0 : (m == 1) ? f1 : f2;
  int t = threadIdx.x, lane = t & 63, wv = t >> 6;
  int row = blockIdx.x * 4 + wv;
  if (row >= n) return;
  const f32x4* rp = (const f32x4*)(F + (long)row * D_DIM) + lane;
  f32x4 b[8];
#pragma unroll
  for (int j = 0; j < 8; ++j) b[j] = rp[64 * j];
  float ssq = 0.f;
#pragma unroll
  for (int j = 0; j < 8; ++j) {
    f32x4 q = b[j] * b[j];
    ssq += q.x + q.y + q.z + q.w;
  }
  ssq = xred_sum(ssq);
  if (lane == 0) wnorm[(long)m * n + row] = 1.0f / fmaxf(sqrtf(ssq), 1e-12f);
}

// R5 pass 2: per (class p, modality m) block. Row weights are precomputed, so
// the main loop is a pure streaming weighted accumulate: load -> FMA -> done,
// no cross-lane ops, no barriers (the norm-then-reuse dependency that defeated
// every one-pass variant is gone). Thread t owns f32x4 column slots t, t+256.
// Epilogue: block-wide center norm + bf16 store.
__global__ __launch_bounds__(256)
void k_centers(const float* __restrict__ f0, const float* __restrict__ f1,
               const float* __restrict__ f2, const int* __restrict__ cnt,
               const int* __restrict__ idx, const float* __restrict__ wnorm,
               __hip_bfloat16* __restrict__ cb, float* __restrict__ accs,
               int n) {
  __shared__ float scr[4];
  int p = blockIdx.x, m = blockIdx.y;
  const float* F = (m == 0) ? f0 : (m == 1) ? f1 : f2;
  int t = threadIdx.x, lane = t & 63, wv = t >> 6;
  int c = cnt[p];
  if (c > CAP) c = CAP;
  const int* idxp = idx + p * CAP;
  const float* wn = wnorm + (long)m * n;

  f32x4 acc0 = {0, 0, 0, 0}, acc1 = {0, 0, 0, 0};
  for (int base = 0; base < c; base += 16) {
    const int4* ip4 = (const int4*)(idxp + base);
    int4 iv0 = ip4[0], iv1 = ip4[1], iv2 = ip4[2], iv3 = ip4[3];
    int rr[16] = {iv0.x, iv0.y, iv0.z, iv0.w, iv1.x, iv1.y, iv1.z, iv1.w,
                  iv2.x, iv2.y, iv2.z, iv2.w, iv3.x, iv3.y, iv3.z, iv3.w};
#pragma unroll
    for (int r = 0; r < 16; ++r) {
      if (base + r < c) {  // block-uniform branch
        int ri = rr[r];
        float wr = wn[ri];
        const f32x4* rp = (const f32x4*)(F + (long)ri * D_DIM);
        acc0 += rp[t] * wr;
        acc1 += rp[t + 256] * wr;
      }
    }
  }

  // center norm across the block (threads own disjoint column slots)
  f32x4 qa = acc0 * acc0, qb = acc1 * acc1;
  float s2 = qa.x + qa.y + qa.z + qa.w + qb.x + qb.y + qb.z + qb.w;
  s2 = xred_sum(s2);
  if (lane == 0) scr[wv] = s2;
  __syncthreads();
  s2 = scr[0] + scr[1] + scr[2] + scr[3];
  float sn = sqrtf(s2);
  float inv = 1.0f / fmaxf(sn, 1e-12f);
  __hip_bfloat16* dst = cb + ((long)m * P_CLS + p) * D_DIM;
  f32x4 o0 = acc0 * inv, o1 = acc1 * inv;
  ushort4 h0, h1;
  h0.x = f2bf_bits(o0.x); h0.y = f2bf_bits(o0.y);
  h0.z = f2bf_bits(o0.z); h0.w = f2bf_bits(o0.w);
  h1.x = f2bf_bits(o1.x); h1.y = f2bf_bits(o1.y);
  h1.z = f2bf_bits(o1.z); h1.w = f2bf_bits(o1.w);
  ((ushort4*)dst)[t] = h0;
  ((ushort4*)dst)[t + 256] = h1;
  if (t == 0 && c > 0) atomicAdd(&accs[0], sn);
}

// Split-K bf16 MFMA GEMM (gridDim.z slices), 64x64 tiles, LDS double-buffer
// + depth-2 reg prefetch, one barrier per K-step.
__global__ __launch_bounds__(256)
void k_gemm(const __hip_bfloat16* __restrict__ cbh, float* __restrict__ logits) {
  __shared__ __align__(16) unsigned short As[2][64 * 40], Bs[2][64 * 40];
  int pair = blockIdx.y, kz = blockIdx.z, nkz = gridDim.z;
  int ksl = D_DIM / nkz;
  int ma = (pair == 2) ? 1 : 0;
  int mb = (pair == 0) ? 1 : 2;
  const unsigned short* A =
      (const unsigned short*)cbh + (long)ma * P_CLS * D_DIM + kz * ksl;
  const unsigned short* B =
      (const unsigned short*)cbh + (long)mb * P_CLS * D_DIM + kz * ksl;
  float* C = logits + ((long)kz * 3 + pair) * P_CLS * P_CLS;
  int tm = (blockIdx.x >> 3) * 64, tn = (blockIdx.x & 7) * 64;
  int t = threadIdx.x, lane = t & 63, wv = t >> 6;
  int srow = t >> 2, skc = (t & 3) * 8;
  int quad = lane >> 4, mr = lane & 15;
  const unsigned short* pa = A + (long)(tm + srow) * D_DIM + skc;
  const unsigned short* pb = B + (long)(tn + srow) * D_DIM + skc;
  f32x4 acc[4] = {{0,0,0,0},{0,0,0,0},{0,0,0,0},{0,0,0,0}};
  uint4 av = *(const uint4*)pa, bv = *(const uint4*)pb;
  *(uint4*)(&As[0][srow * 40 + skc]) = av;
  *(uint4*)(&Bs[0][srow * 40 + skc]) = bv;
  av = *(const uint4*)(pa + 32); bv = *(const uint4*)(pb + 32);
  const int NIT = ksl / 32;
  for (int it = 0; it < NIT; ++it) {
    __syncthreads();
    int cur = it & 1;
    if (it + 1 < NIT) {
      *(uint4*)(&As[cur ^ 1][srow * 40 + skc]) = av;
      *(uint4*)(&Bs[cur ^ 1][srow * 40 + skc]) = bv;
    }
    if (it + 2 < NIT) {
      av = *(const uint4*)(pa + (it + 2) * 32);
      bv = *(const uint4*)(pb + (it + 2) * 32);
    }
    short8 af = *(const short8*)(&As[cur][(wv * 16 + mr) * 40 + quad * 8]);
#pragma unroll
    for (int nb = 0; nb < 4; ++nb) {
      short8 bfr = *(const short8*)(&Bs[cur][(nb * 16 + mr) * 40 + quad * 8]);
      acc[nb] = __builtin_amdgcn_mfma_f32_16x16x32_bf16(af, bfr, acc[nb], 0, 0, 0);
    }
  }
  int crow = tm + wv * 16 + quad * 4;
#pragma unroll
  for (int nb = 0; nb < 4; ++nb)
#pragma unroll
    for (int r = 0; r < 4; ++r)
      C[(long)(crow + r) * P_CLS + tn + nb * 16 + mr] = acc[nb][r] * TAU_INV;
}

// One block per (pair,p) row: sum nkz split-K partials, logsumexp - diag.
__global__ __launch_bounds__(256)
void k_lse(const float* __restrict__ logits, float* __restrict__ accs, int nkz) {
  __shared__ float sred[8];
  int row = blockIdx.x;  // 0 .. 3*P-1
  int p = row & (P_CLS - 1);
  int t = threadIdx.x, lane = t & 63, wv = t >> 6;
  float v0 = 0.f, v1 = 0.f, diag = 0.f;
  for (int z = 0; z < nkz; ++z) {
    const float* L = logits + ((long)z * 3 * P_CLS + row) * P_CLS;
    v0 += L[t];
    v1 += L[t + 256];
  }
  float mx = xred_max(fmaxf(v0, v1));
  if (lane == 0) sred[wv] = mx;
  __syncthreads();
  mx = fmaxf(fmaxf(sred[0], sred[1]), fmaxf(sred[2], sred[3]));
  float e = expf(v0 - mx) + expf(v1 - mx);
  e = xred_sum(e);
  if (lane == 0) sred[4 + wv] = e;
  __syncthreads();
  if (t == 0) {
    float tot = sred[4] + sred[5] + sred[6] + sred[7];
    for (int z = 0; z < nkz; ++z)
      diag += logits[((long)z * 3 * P_CLS + row) * P_CLS + p];
    atomicAdd(&accs[1], mx + logf(tot) - diag);
  }
}

__global__ void k_final(const float* __restrict__ accs, float* __restrict__ out,
                        float invN) {
  out[0] = 6.0f - 2.0f * invN * accs[0] + accs[1] * (1.0f / (float)P_CLS);
}

extern "C" void kernel_launch(void* const* d_in, const int* in_sizes, int n_in,
                              void* d_out, int out_size, void* d_ws, size_t ws_size,
                              hipStream_t stream) {
  const float* fvp = (const float*)d_in[0];
  const float* fap = (const float*)d_in[1];
  const float* frp = (const float*)d_in[2];
  const int* label = (const int*)d_in[3];
  int N = in_sizes[3];

  char* ws = (char*)d_ws;
  int* cnt = (int*)ws;                                    // 2 KiB
  int* idx = (int*)(ws + 2048);                           // 64 KiB
  float* accs = (float*)(ws + 2048 + 65536);              // 32 B
  float* wnorm = (float*)(ws + 69632);                    // 96 KiB (3*N floats)
  __hip_bfloat16* cb = (__hip_bfloat16*)(ws + 262144);    // 6 MiB
  float* logits = (float*)(ws + 262144 + 3ul * P_CLS * D_DIM * 2);

  size_t base = 262144 + 3ul * P_CLS * D_DIM * 2;
  size_t per_z = 3ul * P_CLS * P_CLS * 4;
  int KZ = (ws_size >= base + 4 * per_z) ? 4 : 2;

  hipLaunchKernelGGL(k_init, dim3(1), dim3(512), 0, stream, cnt, accs);
  hipLaunchKernelGGL(k_index, dim3((N + 255) / 256), dim3(256), 0, stream,
                     label, cnt, idx, N);
  hipLaunchKernelGGL(k_norms, dim3((N + 3) / 4, 3), dim3(256), 0, stream,
                     fvp, fap, frp, wnorm, N);
  hipLaunchKernelGGL(k_centers, dim3(P_CLS, 3), dim3(256), 0, stream,
                     fvp, fap, frp, cnt, idx, wnorm, cb, accs, N);
  hipLaunchKernelGGL(k_gemm, dim3(64, 3, KZ), dim3(256), 0, stream, cb, logits);
  hipLaunchKernelGGL(k_lse, dim3(3 * P_CLS), dim3(256), 0, stream, logits, accs, KZ);
  hipLaunchKernelGGL(k_final, dim3(1), dim3(1), 0, stream, accs, (float*)d_out,
                     1.0f / (float)N);
}

// Round 6
// 240.788 us; speedup vs baseline: 1.1499x; 1.1499x over previous
//
#include <hip/hip_runtime.h>
#include <hip/hip_bf16.h>

#define P_CLS 512
#define D_DIM 2048
#define CAP   32
#define TAU_INV 2.0f

typedef short short8 __attribute__((ext_vector_type(8)));
typedef float f32x4 __attribute__((ext_vector_type(4)));

__device__ __forceinline__ unsigned short f2bf_bits(float x) {
  __hip_bfloat16 b = __float2bfloat16(x);
  unsigned short u;
  __builtin_memcpy(&u, &b, sizeof(u));
  return u;
}

__device__ __forceinline__ float xred_sum(float v) {
#pragma unroll
  for (int o = 1; o < 64; o <<= 1) v += __shfl_xor(v, o, 64);
  return v;
}
__device__ __forceinline__ float xred_max(float v) {
#pragma unroll
  for (int o = 1; o < 64; o <<= 1) v = fmaxf(v, __shfl_xor(v, o, 64));
  return v;
}

__global__ void k_init(int* cnt, float* accs) {
  int t = blockIdx.x * blockDim.x + threadIdx.x;
  if (t < P_CLS) cnt[t] = 0;
  if (t < 8) accs[t] = 0.f;
}

__global__ void k_index(const int* __restrict__ label, int* __restrict__ cnt,
                        int* __restrict__ idx, int n) {
  int i = blockIdx.x * blockDim.x + threadIdx.x;
  if (i < n) {
    int p = label[i];
    int slot = atomicAdd(&cnt[p], 1);
    if (slot < CAP) idx[p * CAP + slot] = i;
  }
}

// R6: one-pass k_centers, R1 wave-per-row skeleton + VALUE PINNING.
// Each loaded row value is routed through asm volatile("" : "+v"(x)):
// the consumer uses the asm OUTPUT, which cannot be rematerialized or
// reloaded (re-executing a volatile asm is forbidden), so the compiler
// must keep all 3 row buffers (depth-3 pipeline, 24 KB/wave in flight)
// genuinely live and their loads batched. Row indices preloaded so idx
// latency is off the critical path. No barrier in the main loop.
__global__ __launch_bounds__(256)
void k_centers(const float* __restrict__ f0, const float* __restrict__ f1,
               const float* __restrict__ f2, const int* __restrict__ cnt,
               const int* __restrict__ idx, __hip_bfloat16* __restrict__ cb,
               float* __restrict__ accs) {
  __shared__ __align__(16) f32x4 red[4][D_DIM / 4];  // 32 KiB
  __shared__ float scr[4];
  int p = blockIdx.x, m = blockIdx.y;
  const float* F = (m == 0) ? f0 : (m == 1) ? f1 : f2;
  int t = threadIdx.x, lane = t & 63, wv = t >> 6;
  int c = cnt[p];
  if (c > CAP) c = CAP;
  const int* idxp = idx + p * CAP;

  // wave wv handles rows wv + 4k, k < nr (nr <= 8)
  int nr = (c > wv) ? ((c - wv + 3) >> 2) : 0;

  const f32x4* rp[8];
#pragma unroll
  for (int k = 0; k < 8; ++k) {
    int r = wv + 4 * k;
    int rc = (r < c) ? r : 0;
    rp[k] = (c > 0) ? (const f32x4*)(F + (long)idxp[rc] * D_DIM) + lane
                    : (const f32x4*)F + lane;
  }

  f32x4 acc[8] = {{0,0,0,0},{0,0,0,0},{0,0,0,0},{0,0,0,0},
                  {0,0,0,0},{0,0,0,0},{0,0,0,0},{0,0,0,0}};
  f32x4 ba[8], bb[8], bd[8];

  auto loadrow = [&](f32x4* buf, const f32x4* src) {
#pragma unroll
    for (int j = 0; j < 8; ++j) buf[j] = src[64 * j];
    // Pin: buf values become volatile-asm outputs -> must be materialized
    // together here; cannot be sunk, split, or reloaded later.
    asm volatile("" : "+v"(buf[0]), "+v"(buf[1]), "+v"(buf[2]), "+v"(buf[3]),
                      "+v"(buf[4]), "+v"(buf[5]), "+v"(buf[6]), "+v"(buf[7]));
  };
  auto consume = [&](const f32x4* buf) {
    float ssq = 0.f;
#pragma unroll
    for (int j = 0; j < 8; ++j) {
      f32x4 q = buf[j] * buf[j];
      ssq += q.x + q.y + q.z + q.w;
    }
    ssq = xred_sum(ssq);
    float w = 1.0f / fmaxf(sqrtf(ssq), 1e-12f);
#pragma unroll
    for (int j = 0; j < 8; ++j) acc[j] += buf[j] * w;
  };

  if (nr > 0) loadrow(ba, rp[0]);
  if (nr > 1) loadrow(bb, rp[1]);
  if (nr > 2) loadrow(bd, rp[2]);
#pragma unroll
  for (int k = 0; k < 8; ++k) {
    f32x4* cur = (k % 3 == 0) ? ba : (k % 3 == 1) ? bb : bd;
    if (k < nr) consume(cur);
    if (k + 3 < nr) loadrow(cur, rp[k + 3]);
  }

  // merge the 4 wave accumulators; acc[j] is the row f32x4 at vector index
  // lane + 64*j, so red[wv] laid out by that index is the row in natural order.
#pragma unroll
  for (int j = 0; j < 8; ++j) red[wv][lane + 64 * j] = acc[j];
  __syncthreads();
  f32x4 s0 = red[0][t] + red[1][t] + red[2][t] + red[3][t];
  f32x4 s1 = red[0][t + 256] + red[1][t + 256] + red[2][t + 256] + red[3][t + 256];
  f32x4 q0 = s0 * s0, q1 = s1 * s1;
  float s2 = q0.x + q0.y + q0.z + q0.w + q1.x + q1.y + q1.z + q1.w;
  s2 = xred_sum(s2);
  if (lane == 0) scr[wv] = s2;
  __syncthreads();
  s2 = scr[0] + scr[1] + scr[2] + scr[3];
  float sn = sqrtf(s2);
  float inv = 1.0f / fmaxf(sn, 1e-12f);
  __hip_bfloat16* dst = cb + ((long)m * P_CLS + p) * D_DIM;
  f32x4 o0 = s0 * inv, o1 = s1 * inv;
  ushort4 h0, h1;
  h0.x = f2bf_bits(o0.x); h0.y = f2bf_bits(o0.y);
  h0.z = f2bf_bits(o0.z); h0.w = f2bf_bits(o0.w);
  h1.x = f2bf_bits(o1.x); h1.y = f2bf_bits(o1.y);
  h1.z = f2bf_bits(o1.z); h1.w = f2bf_bits(o1.w);
  ((ushort4*)dst)[t] = h0;
  ((ushort4*)dst)[t + 256] = h1;
  if (t == 0 && c > 0) atomicAdd(&accs[0], sn);
}

// Split-K bf16 MFMA GEMM (gridDim.z slices), 64x64 tiles, LDS double-buffer
// + depth-2 reg prefetch, one barrier per K-step.
__global__ __launch_bounds__(256)
void k_gemm(const __hip_bfloat16* __restrict__ cbh, float* __restrict__ logits) {
  __shared__ __align__(16) unsigned short As[2][64 * 40], Bs[2][64 * 40];
  int pair = blockIdx.y, kz = blockIdx.z, nkz = gridDim.z;
  int ksl = D_DIM / nkz;
  int ma = (pair == 2) ? 1 : 0;
  int mb = (pair == 0) ? 1 : 2;
  const unsigned short* A =
      (const unsigned short*)cbh + (long)ma * P_CLS * D_DIM + kz * ksl;
  const unsigned short* B =
      (const unsigned short*)cbh + (long)mb * P_CLS * D_DIM + kz * ksl;
  float* C = logits + ((long)kz * 3 + pair) * P_CLS * P_CLS;
  int tm = (blockIdx.x >> 3) * 64, tn = (blockIdx.x & 7) * 64;
  int t = threadIdx.x, lane = t & 63, wv = t >> 6;
  int srow = t >> 2, skc = (t & 3) * 8;
  int quad = lane >> 4, mr = lane & 15;
  const unsigned short* pa = A + (long)(tm + srow) * D_DIM + skc;
  const unsigned short* pb = B + (long)(tn + srow) * D_DIM + skc;
  f32x4 acc[4] = {{0,0,0,0},{0,0,0,0},{0,0,0,0},{0,0,0,0}};
  uint4 av = *(const uint4*)pa, bv = *(const uint4*)pb;
  *(uint4*)(&As[0][srow * 40 + skc]) = av;
  *(uint4*)(&Bs[0][srow * 40 + skc]) = bv;
  av = *(const uint4*)(pa + 32); bv = *(const uint4*)(pb + 32);
  const int NIT = ksl / 32;
  for (int it = 0; it < NIT; ++it) {
    __syncthreads();
    int cur = it & 1;
    if (it + 1 < NIT) {
      *(uint4*)(&As[cur ^ 1][srow * 40 + skc]) = av;
      *(uint4*)(&Bs[cur ^ 1][srow * 40 + skc]) = bv;
    }
    if (it + 2 < NIT) {
      av = *(const uint4*)(pa + (it + 2) * 32);
      bv = *(const uint4*)(pb + (it + 2) * 32);
    }
    short8 af = *(const short8*)(&As[cur][(wv * 16 + mr) * 40 + quad * 8]);
#pragma unroll
    for (int nb = 0; nb < 4; ++nb) {
      short8 bfr = *(const short8*)(&Bs[cur][(nb * 16 + mr) * 40 + quad * 8]);
      acc[nb] = __builtin_amdgcn_mfma_f32_16x16x32_bf16(af, bfr, acc[nb], 0, 0, 0);
    }
  }
  int crow = tm + wv * 16 + quad * 4;
#pragma unroll
  for (int nb = 0; nb < 4; ++nb)
#pragma unroll
    for (int r = 0; r < 4; ++r)
      C[(long)(crow + r) * P_CLS + tn + nb * 16 + mr] = acc[nb][r] * TAU_INV;
}

// One block per (pair,p) row: sum nkz split-K partials, logsumexp - diag.
__global__ __launch_bounds__(256)
void k_lse(const float* __restrict__ logits, float* __restrict__ accs, int nkz) {
  __shared__ float sred[8];
  int row = blockIdx.x;  // 0 .. 3*P-1
  int p = row & (P_CLS - 1);
  int t = threadIdx.x, lane = t & 63, wv = t >> 6;
  float v0 = 0.f, v1 = 0.f, diag = 0.f;
  for (int z = 0; z < nkz; ++z) {
    const float* L = logits + ((long)z * 3 * P_CLS + row) * P_CLS;
    v0 += L[t];
    v1 += L[t + 256];
  }
  float mx = xred_max(fmaxf(v0, v1));
  if (lane == 0) sred[wv] = mx;
  __syncthreads();
  mx = fmaxf(fmaxf(sred[0], sred[1]), fmaxf(sred[2], sred[3]));
  float e = expf(v0 - mx) + expf(v1 - mx);
  e = xred_sum(e);
  if (lane == 0) sred[4 + wv] = e;
  __syncthreads();
  if (t == 0) {
    float tot = sred[4] + sred[5] + sred[6] + sred[7];
    for (int z = 0; z < nkz; ++z)
      diag += logits[((long)z * 3 * P_CLS + row) * P_CLS + p];
    atomicAdd(&accs[1], mx + logf(tot) - diag);
  }
}

__global__ void k_final(const float* __restrict__ accs, float* __restrict__ out,
                        float invN) {
  out[0] = 6.0f - 2.0f * invN * accs[0] + accs[1] * (1.0f / (float)P_CLS);
}

extern "C" void kernel_launch(void* const* d_in, const int* in_sizes, int n_in,
                              void* d_out, int out_size, void* d_ws, size_t ws_size,
                              hipStream_t stream) {
  const float* fvp = (const float*)d_in[0];
  const float* fap = (const float*)d_in[1];
  const float* frp = (const float*)d_in[2];
  const int* label = (const int*)d_in[3];
  int N = in_sizes[3];

  char* ws = (char*)d_ws;
  int* cnt = (int*)ws;                                    // 2 KiB
  int* idx = (int*)(ws + 2048);                           // 64 KiB
  float* accs = (float*)(ws + 2048 + 65536);              // 32 B
  __hip_bfloat16* cb = (__hip_bfloat16*)(ws + 131072);    // 6 MiB
  float* logits = (float*)(ws + 131072 + 3ul * P_CLS * D_DIM * 2);

  size_t base = 131072 + 3ul * P_CLS * D_DIM * 2;
  size_t per_z = 3ul * P_CLS * P_CLS * 4;
  int KZ = (ws_size >= base + 4 * per_z) ? 4 : 2;

  hipLaunchKernelGGL(k_init, dim3(1), dim3(512), 0, stream, cnt, accs);
  hipLaunchKernelGGL(k_index, dim3((N + 255) / 256), dim3(256), 0, stream,
                     label, cnt, idx, N);
  hipLaunchKernelGGL(k_centers, dim3(P_CLS, 3), dim3(256), 0, stream,
                     fvp, fap, frp, cnt, idx, cb, accs);
  hipLaunchKernelGGL(k_gemm, dim3(64, 3, KZ), dim3(256), 0, stream, cb, logits);
  hipLaunchKernelGGL(k_lse, dim3(3 * P_CLS), dim3(256), 0, stream, logits, accs, KZ);
  hipLaunchKernelGGL(k_final, dim3(1), dim3(1), 0, stream, accs, (float*)d_out,
                     1.0f / (float)N);
}

// Round 7
// 223.677 us; speedup vs baseline: 1.2379x; 1.0765x over previous
//
#include <hip/hip_runtime.h>
#include <hip/hip_bf16.h>

#define P_CLS 512
#define D_DIM 2048
#define CAP   32
#define TAU_INV 2.0f

typedef short short8 __attribute__((ext_vector_type(8)));
typedef float f32x4 __attribute__((ext_vector_type(4)));

__device__ __forceinline__ unsigned short f2bf_bits(float x) {
  __hip_bfloat16 b = __float2bfloat16(x);
  unsigned short u;
  __builtin_memcpy(&u, &b, sizeof(u));
  return u;
}

__device__ __forceinline__ float xred_sum(float v) {
#pragma unroll
  for (int o = 1; o < 64; o <<= 1) v += __shfl_xor(v, o, 64);
  return v;
}
__device__ __forceinline__ float xred_max(float v) {
#pragma unroll
  for (int o = 1; o < 64; o <<= 1) v = fmaxf(v, __shfl_xor(v, o, 64));
  return v;
}

__global__ void k_init(int* cnt, float* accs) {
  int t = blockIdx.x * blockDim.x + threadIdx.x;
  if (t < P_CLS) cnt[t] = 0;
  if (t < 8) accs[t] = 0.f;
}

__global__ void k_index(const int* __restrict__ label, int* __restrict__ cnt,
                        int* __restrict__ idx, int n) {
  int i = blockIdx.x * blockDim.x + threadIdx.x;
  if (i < n) {
    int p = label[i];
    int slot = atomicAdd(&cnt[p], 1);
    if (slot < CAP) idx[p * CAP + slot] = i;
  }
}

// k_centers: R1/R6 wave-per-row one-pass structure (closed at ~80 us; L3-warm
// replays show the same duration, so it is latency-floor-bound, not BW-bound).
__global__ __launch_bounds__(256)
void k_centers(const float* __restrict__ f0, const float* __restrict__ f1,
               const float* __restrict__ f2, const int* __restrict__ cnt,
               const int* __restrict__ idx, __hip_bfloat16* __restrict__ cb,
               float* __restrict__ accs) {
  __shared__ __align__(16) f32x4 red[4][D_DIM / 4];  // 32 KiB
  __shared__ float scr[4];
  int p = blockIdx.x, m = blockIdx.y;
  const float* F = (m == 0) ? f0 : (m == 1) ? f1 : f2;
  int t = threadIdx.x, lane = t & 63, wv = t >> 6;
  int c = cnt[p];
  if (c > CAP) c = CAP;
  const int* idxp = idx + p * CAP;

  int nr = (c > wv) ? ((c - wv + 3) >> 2) : 0;

  const f32x4* rp[8];
#pragma unroll
  for (int k = 0; k < 8; ++k) {
    int r = wv + 4 * k;
    int rc = (r < c) ? r : 0;
    rp[k] = (c > 0) ? (const f32x4*)(F + (long)idxp[rc] * D_DIM) + lane
                    : (const f32x4*)F + lane;
  }

  f32x4 acc[8] = {{0,0,0,0},{0,0,0,0},{0,0,0,0},{0,0,0,0},
                  {0,0,0,0},{0,0,0,0},{0,0,0,0},{0,0,0,0}};
  f32x4 ba[8], bb[8], bd[8];

  auto loadrow = [&](f32x4* buf, const f32x4* src) {
#pragma unroll
    for (int j = 0; j < 8; ++j) buf[j] = src[64 * j];
    asm volatile("" : "+v"(buf[0]), "+v"(buf[1]), "+v"(buf[2]), "+v"(buf[3]),
                      "+v"(buf[4]), "+v"(buf[5]), "+v"(buf[6]), "+v"(buf[7]));
  };
  auto consume = [&](const f32x4* buf) {
    float ssq = 0.f;
#pragma unroll
    for (int j = 0; j < 8; ++j) {
      f32x4 q = buf[j] * buf[j];
      ssq += q.x + q.y + q.z + q.w;
    }
    ssq = xred_sum(ssq);
    float w = 1.0f / fmaxf(sqrtf(ssq), 1e-12f);
#pragma unroll
    for (int j = 0; j < 8; ++j) acc[j] += buf[j] * w;
  };

  if (nr > 0) loadrow(ba, rp[0]);
  if (nr > 1) loadrow(bb, rp[1]);
  if (nr > 2) loadrow(bd, rp[2]);
#pragma unroll
  for (int k = 0; k < 8; ++k) {
    f32x4* cur = (k % 3 == 0) ? ba : (k % 3 == 1) ? bb : bd;
    if (k < nr) consume(cur);
    if (k + 3 < nr) loadrow(cur, rp[k + 3]);
  }

#pragma unroll
  for (int j = 0; j < 8; ++j) red[wv][lane + 64 * j] = acc[j];
  __syncthreads();
  f32x4 s0 = red[0][t] + red[1][t] + red[2][t] + red[3][t];
  f32x4 s1 = red[0][t + 256] + red[1][t + 256] + red[2][t + 256] + red[3][t + 256];
  f32x4 q0 = s0 * s0, q1 = s1 * s1;
  float s2 = q0.x + q0.y + q0.z + q0.w + q1.x + q1.y + q1.z + q1.w;
  s2 = xred_sum(s2);
  if (lane == 0) scr[wv] = s2;
  __syncthreads();
  s2 = scr[0] + scr[1] + scr[2] + scr[3];
  float sn = sqrtf(s2);
  float inv = 1.0f / fmaxf(sn, 1e-12f);
  __hip_bfloat16* dst = cb + ((long)m * P_CLS + p) * D_DIM;
  f32x4 o0 = s0 * inv, o1 = s1 * inv;
  ushort4 h0, h1;
  h0.x = f2bf_bits(o0.x); h0.y = f2bf_bits(o0.y);
  h0.z = f2bf_bits(o0.z); h0.w = f2bf_bits(o0.w);
  h1.x = f2bf_bits(o1.x); h1.y = f2bf_bits(o1.y);
  h1.z = f2bf_bits(o1.z); h1.w = f2bf_bits(o1.w);
  ((ushort4*)dst)[t] = h0;
  ((ushort4*)dst)[t + 256] = h1;
  if (t == 0 && c > 0) atomicAdd(&accs[0], sn);
}

// R7: 128x128 tile split-K bf16 MFMA GEMM. 2x2 wave grid, each wave owns a
// 64x64 output (4x4 16x16x32 frags) -> 16 MFMA : 8 ds_read per barrier
// (vs 4:5 at 64x64), 4x fewer blocks each with 4x the work. LDS 40 KiB
// double-buffered, depth-2 register prefetch, one barrier per K-step.
__global__ __launch_bounds__(256)
void k_gemm(const __hip_bfloat16* __restrict__ cbh, float* __restrict__ logits) {
  __shared__ __align__(16) unsigned short As[2][128 * 40], Bs[2][128 * 40];
  int pair = blockIdx.y, kz = blockIdx.z, nkz = gridDim.z;
  int ksl = D_DIM / nkz;
  int ma = (pair == 2) ? 1 : 0;
  int mb = (pair == 0) ? 1 : 2;
  const unsigned short* A =
      (const unsigned short*)cbh + (long)ma * P_CLS * D_DIM + kz * ksl;
  const unsigned short* B =
      (const unsigned short*)cbh + (long)mb * P_CLS * D_DIM + kz * ksl;
  float* C = logits + ((long)kz * 3 + pair) * P_CLS * P_CLS;
  int tm = (blockIdx.x & 3) * 128, tn = (blockIdx.x >> 2) * 128;
  int t = threadIdx.x, lane = t & 63, wv = t >> 6;
  int quad = lane >> 4, mr = lane & 15;
  int wr = (wv >> 1) * 64, wc = (wv & 1) * 64;
  // staging: 2 uint4 chunks per thread per matrix per K-step
  int sr0 = t >> 2, sc0 = (t & 3) * 8;
  int sr1 = (t + 256) >> 2, sc1 = ((t + 256) & 3) * 8;
  const unsigned short* pa0 = A + (long)(tm + sr0) * D_DIM + sc0;
  const unsigned short* pa1 = A + (long)(tm + sr1) * D_DIM + sc1;
  const unsigned short* pb0 = B + (long)(tn + sr0) * D_DIM + sc0;
  const unsigned short* pb1 = B + (long)(tn + sr1) * D_DIM + sc1;
  int l0 = sr0 * 40 + sc0, l1 = sr1 * 40 + sc1;

  f32x4 acc[4][4];
#pragma unroll
  for (int i = 0; i < 4; ++i)
#pragma unroll
    for (int j = 0; j < 4; ++j) acc[i][j] = {0, 0, 0, 0};

  uint4 a0 = *(const uint4*)pa0, a1 = *(const uint4*)pa1;
  uint4 b0 = *(const uint4*)pb0, b1 = *(const uint4*)pb1;
  *(uint4*)(&As[0][l0]) = a0; *(uint4*)(&As[0][l1]) = a1;
  *(uint4*)(&Bs[0][l0]) = b0; *(uint4*)(&Bs[0][l1]) = b1;
  a0 = *(const uint4*)(pa0 + 32); a1 = *(const uint4*)(pa1 + 32);
  b0 = *(const uint4*)(pb0 + 32); b1 = *(const uint4*)(pb1 + 32);

  const int NIT = ksl / 32;
  for (int it = 0; it < NIT; ++it) {
    __syncthreads();
    int cur = it & 1;
    if (it + 1 < NIT) {
      *(uint4*)(&As[cur ^ 1][l0]) = a0; *(uint4*)(&As[cur ^ 1][l1]) = a1;
      *(uint4*)(&Bs[cur ^ 1][l0]) = b0; *(uint4*)(&Bs[cur ^ 1][l1]) = b1;
    }
    if (it + 2 < NIT) {
      a0 = *(const uint4*)(pa0 + (it + 2) * 32);
      a1 = *(const uint4*)(pa1 + (it + 2) * 32);
      b0 = *(const uint4*)(pb0 + (it + 2) * 32);
      b1 = *(const uint4*)(pb1 + (it + 2) * 32);
    }
    short8 af[4], bf[4];
#pragma unroll
    for (int i = 0; i < 4; ++i)
      af[i] = *(const short8*)(&As[cur][(wr + i * 16 + mr) * 40 + quad * 8]);
#pragma unroll
    for (int j = 0; j < 4; ++j)
      bf[j] = *(const short8*)(&Bs[cur][(wc + j * 16 + mr) * 40 + quad * 8]);
#pragma unroll
    for (int i = 0; i < 4; ++i)
#pragma unroll
      for (int j = 0; j < 4; ++j)
        acc[i][j] = __builtin_amdgcn_mfma_f32_16x16x32_bf16(af[i], bf[j],
                                                            acc[i][j], 0, 0, 0);
  }
#pragma unroll
  for (int i = 0; i < 4; ++i) {
    int crow = tm + wr + i * 16 + quad * 4;
#pragma unroll
    for (int j = 0; j < 4; ++j) {
      int ccol = tn + wc + j * 16 + mr;
#pragma unroll
      for (int r = 0; r < 4; ++r)
        C[(long)(crow + r) * P_CLS + ccol] = acc[i][j][r] * TAU_INV;
    }
  }
}

// One block per (pair,p) row: sum nkz split-K partials, logsumexp - diag.
// R7: no global atomic (stores per-row result to lsep); diag recovered from
// the already-summed column values (no serial thread-0 reload tail).
__global__ __launch_bounds__(256)
void k_lse(const float* __restrict__ logits, float* __restrict__ lsep, int nkz) {
  __shared__ float sred[12];
  int row = blockIdx.x;  // 0 .. 3*P-1
  int p = row & (P_CLS - 1);
  int t = threadIdx.x, lane = t & 63, wv = t >> 6;
  float v0 = 0.f, v1 = 0.f;
  for (int z = 0; z < nkz; ++z) {
    const float* L = logits + ((long)z * 3 * P_CLS + row) * P_CLS;
    v0 += L[t];
    v1 += L[t + 256];
  }
  float dg = 0.f;
  if (t == p) dg = v0;
  if (t + 256 == p) dg = v1;
  float mx = xred_max(fmaxf(v0, v1));
  if (lane == 0) sred[wv] = mx;
  __syncthreads();
  mx = fmaxf(fmaxf(sred[0], sred[1]), fmaxf(sred[2], sred[3]));
  float e = expf(v0 - mx) + expf(v1 - mx);
  e = xred_sum(e);
  dg = xred_sum(dg);
  if (lane == 0) { sred[4 + wv] = e; sred[8 + wv] = dg; }
  __syncthreads();
  if (t == 0) {
    float tot = sred[4] + sred[5] + sred[6] + sred[7];
    float dgt = sred[8] + sred[9] + sred[10] + sred[11];
    lsep[row] = mx + logf(tot) - dgt;
  }
}

// Single 256-thread block: reduce the 1536 per-row LSE values + combine.
__global__ __launch_bounds__(256)
void k_final(const float* __restrict__ accs, const float* __restrict__ lsep,
             float* __restrict__ out, float invN) {
  __shared__ float sr[4];
  int t = threadIdx.x, lane = t & 63, wv = t >> 6;
  float s = 0.f;
#pragma unroll
  for (int i = 0; i < 6; ++i) s += lsep[t + 256 * i];
  s = xred_sum(s);
  if (lane == 0) sr[wv] = s;
  __syncthreads();
  if (t == 0) {
    float tot = sr[0] + sr[1] + sr[2] + sr[3];
    out[0] = 6.0f - 2.0f * invN * accs[0] + tot * (1.0f / (float)P_CLS);
  }
}

extern "C" void kernel_launch(void* const* d_in, const int* in_sizes, int n_in,
                              void* d_out, int out_size, void* d_ws, size_t ws_size,
                              hipStream_t stream) {
  const float* fvp = (const float*)d_in[0];
  const float* fap = (const float*)d_in[1];
  const float* frp = (const float*)d_in[2];
  const int* label = (const int*)d_in[3];
  int N = in_sizes[3];

  char* ws = (char*)d_ws;
  int* cnt = (int*)ws;                                    // 2 KiB
  int* idx = (int*)(ws + 2048);                           // 64 KiB
  float* accs = (float*)(ws + 2048 + 65536);              // 32 B
  float* lsep = (float*)(ws + 69632);                     // 6 KiB (1536 f32)
  __hip_bfloat16* cb = (__hip_bfloat16*)(ws + 131072);    // 6 MiB
  float* logits = (float*)(ws + 131072 + 3ul * P_CLS * D_DIM * 2);

  size_t base = 131072 + 3ul * P_CLS * D_DIM * 2;
  size_t per_z = 3ul * P_CLS * P_CLS * 4;
  int KZ = (ws_size >= base + 8 * per_z) ? 8
         : (ws_size >= base + 4 * per_z) ? 4 : 2;

  hipLaunchKernelGGL(k_init, dim3(1), dim3(512), 0, stream, cnt, accs);
  hipLaunchKernelGGL(k_index, dim3((N + 255) / 256), dim3(256), 0, stream,
                     label, cnt, idx, N);
  hipLaunchKernelGGL(k_centers, dim3(P_CLS, 3), dim3(256), 0, stream,
                     fvp, fap, frp, cnt, idx, cb, accs);
  hipLaunchKernelGGL(k_gemm, dim3(16, 3, KZ), dim3(256), 0, stream, cb, logits);
  hipLaunchKernelGGL(k_lse, dim3(3 * P_CLS), dim3(256), 0, stream, logits, lsep, KZ);
  hipLaunchKernelGGL(k_final, dim3(1), dim3(256), 0, stream, accs, lsep,
                     (float*)d_out, 1.0f / (float)N);
}

// Round 8
// 220.681 us; speedup vs baseline: 1.2547x; 1.0136x over previous
//
#include <hip/hip_runtime.h>
#include <hip/hip_bf16.h>

#define P_CLS 512
#define D_DIM 2048
#define CAP   32
#define TAU_INV 2.0f

typedef short short8 __attribute__((ext_vector_type(8)));
typedef float f32x4 __attribute__((ext_vector_type(4)));

__device__ __forceinline__ unsigned short f2bf_bits(float x) {
  __hip_bfloat16 b = __float2bfloat16(x);
  unsigned short u;
  __builtin_memcpy(&u, &b, sizeof(u));
  return u;
}

__device__ __forceinline__ float xred_sum(float v) {
#pragma unroll
  for (int o = 1; o < 64; o <<= 1) v += __shfl_xor(v, o, 64);
  return v;
}
__device__ __forceinline__ float xred_max(float v) {
#pragma unroll
  for (int o = 1; o < 64; o <<= 1) v = fmaxf(v, __shfl_xor(v, o, 64));
  return v;
}

// R8: self-indexing k_centers — each (class p, modality m) block scans the
// 32 KB label array itself (int4 loads, L2-resident; LDS atomic append).
// Kills k_init + k_index launches AND the full-grid index->centers
// serialization bubble. Sum order is arbitrary (proven safe: R3's
// nondeterministic LDS-float-atomic variant passed with absmax 0).
// Center path = R6 wave-per-row pipeline (closed at ~80 us, latency-floor).
// No global atomic: per-block sn stored to snbuf, reduced in k_final.
__global__ __launch_bounds__(256)
void k_centers(const float* __restrict__ f0, const float* __restrict__ f1,
               const float* __restrict__ f2, const int* __restrict__ label,
               int n, __hip_bfloat16* __restrict__ cb,
               float* __restrict__ snbuf) {
  __shared__ __align__(16) f32x4 red[4][D_DIM / 4];  // 32 KiB
  __shared__ float scr[4];
  __shared__ int lidx[CAP];
  __shared__ int lcnt;
  int p = blockIdx.x, m = blockIdx.y;
  const float* F = (m == 0) ? f0 : (m == 1) ? f1 : f2;
  int t = threadIdx.x, lane = t & 63, wv = t >> 6;

  if (t == 0) lcnt = 0;
  __syncthreads();
  const int4* lab4 = (const int4*)label;
  int n4 = n >> 2;
  for (int i = t; i < n4; i += 256) {
    int4 lv = lab4[i];
    if (lv.x == p) { int s = atomicAdd(&lcnt, 1); if (s < CAP) lidx[s] = 4 * i; }
    if (lv.y == p) { int s = atomicAdd(&lcnt, 1); if (s < CAP) lidx[s] = 4 * i + 1; }
    if (lv.z == p) { int s = atomicAdd(&lcnt, 1); if (s < CAP) lidx[s] = 4 * i + 2; }
    if (lv.w == p) { int s = atomicAdd(&lcnt, 1); if (s < CAP) lidx[s] = 4 * i + 3; }
  }
  __syncthreads();
  int c = lcnt;
  if (c > CAP) c = CAP;

  int nr = (c > wv) ? ((c - wv + 3) >> 2) : 0;

  const f32x4* rp[8];
#pragma unroll
  for (int k = 0; k < 8; ++k) {
    int r = wv + 4 * k;
    int rc = (r < c) ? r : 0;
    rp[k] = (c > 0) ? (const f32x4*)(F + (long)lidx[rc] * D_DIM) + lane
                    : (const f32x4*)F + lane;
  }

  f32x4 acc[8] = {{0,0,0,0},{0,0,0,0},{0,0,0,0},{0,0,0,0},
                  {0,0,0,0},{0,0,0,0},{0,0,0,0},{0,0,0,0}};
  f32x4 ba[8], bb[8], bd[8];

  auto loadrow = [&](f32x4* buf, const f32x4* src) {
#pragma unroll
    for (int j = 0; j < 8; ++j) buf[j] = src[64 * j];
    asm volatile("" : "+v"(buf[0]), "+v"(buf[1]), "+v"(buf[2]), "+v"(buf[3]),
                      "+v"(buf[4]), "+v"(buf[5]), "+v"(buf[6]), "+v"(buf[7]));
  };
  auto consume = [&](const f32x4* buf) {
    float ssq = 0.f;
#pragma unroll
    for (int j = 0; j < 8; ++j) {
      f32x4 q = buf[j] * buf[j];
      ssq += q.x + q.y + q.z + q.w;
    }
    ssq = xred_sum(ssq);
    float w = 1.0f / fmaxf(sqrtf(ssq), 1e-12f);
#pragma unroll
    for (int j = 0; j < 8; ++j) acc[j] += buf[j] * w;
  };

  if (nr > 0) loadrow(ba, rp[0]);
  if (nr > 1) loadrow(bb, rp[1]);
  if (nr > 2) loadrow(bd, rp[2]);
#pragma unroll
  for (int k = 0; k < 8; ++k) {
    f32x4* cur = (k % 3 == 0) ? ba : (k % 3 == 1) ? bb : bd;
    if (k < nr) consume(cur);
    if (k + 3 < nr) loadrow(cur, rp[k + 3]);
  }

#pragma unroll
  for (int j = 0; j < 8; ++j) red[wv][lane + 64 * j] = acc[j];
  __syncthreads();
  f32x4 s0 = red[0][t] + red[1][t] + red[2][t] + red[3][t];
  f32x4 s1 = red[0][t + 256] + red[1][t + 256] + red[2][t + 256] + red[3][t + 256];
  f32x4 q0 = s0 * s0, q1 = s1 * s1;
  float s2 = q0.x + q0.y + q0.z + q0.w + q1.x + q1.y + q1.z + q1.w;
  s2 = xred_sum(s2);
  if (lane == 0) scr[wv] = s2;
  __syncthreads();
  s2 = scr[0] + scr[1] + scr[2] + scr[3];
  float sn = sqrtf(s2);
  float inv = 1.0f / fmaxf(sn, 1e-12f);
  __hip_bfloat16* dst = cb + ((long)m * P_CLS + p) * D_DIM;
  f32x4 o0 = s0 * inv, o1 = s1 * inv;
  ushort4 h0, h1;
  h0.x = f2bf_bits(o0.x); h0.y = f2bf_bits(o0.y);
  h0.z = f2bf_bits(o0.z); h0.w = f2bf_bits(o0.w);
  h1.x = f2bf_bits(o1.x); h1.y = f2bf_bits(o1.y);
  h1.z = f2bf_bits(o1.z); h1.w = f2bf_bits(o1.w);
  ((ushort4*)dst)[t] = h0;
  ((ushort4*)dst)[t + 256] = h1;
  if (t == 0) snbuf[m * P_CLS + p] = (c > 0) ? sn : 0.f;
}

// 128x128 tile split-K bf16 MFMA GEMM (R7 structure, proven). KZ=4.
__global__ __launch_bounds__(256)
void k_gemm(const __hip_bfloat16* __restrict__ cbh, float* __restrict__ logits) {
  __shared__ __align__(16) unsigned short As[2][128 * 40], Bs[2][128 * 40];
  int pair = blockIdx.y, kz = blockIdx.z, nkz = gridDim.z;
  int ksl = D_DIM / nkz;
  int ma = (pair == 2) ? 1 : 0;
  int mb = (pair == 0) ? 1 : 2;
  const unsigned short* A =
      (const unsigned short*)cbh + (long)ma * P_CLS * D_DIM + kz * ksl;
  const unsigned short* B =
      (const unsigned short*)cbh + (long)mb * P_CLS * D_DIM + kz * ksl;
  float* C = logits + ((long)kz * 3 + pair) * P_CLS * P_CLS;
  int tm = (blockIdx.x & 3) * 128, tn = (blockIdx.x >> 2) * 128;
  int t = threadIdx.x, lane = t & 63, wv = t >> 6;
  int quad = lane >> 4, mr = lane & 15;
  int wr = (wv >> 1) * 64, wc = (wv & 1) * 64;
  int sr0 = t >> 2, sc0 = (t & 3) * 8;
  int sr1 = (t + 256) >> 2, sc1 = ((t + 256) & 3) * 8;
  const unsigned short* pa0 = A + (long)(tm + sr0) * D_DIM + sc0;
  const unsigned short* pa1 = A + (long)(tm + sr1) * D_DIM + sc1;
  const unsigned short* pb0 = B + (long)(tn + sr0) * D_DIM + sc0;
  const unsigned short* pb1 = B + (long)(tn + sr1) * D_DIM + sc1;
  int l0 = sr0 * 40 + sc0, l1 = sr1 * 40 + sc1;

  f32x4 acc[4][4];
#pragma unroll
  for (int i = 0; i < 4; ++i)
#pragma unroll
    for (int j = 0; j < 4; ++j) acc[i][j] = {0, 0, 0, 0};

  uint4 a0 = *(const uint4*)pa0, a1 = *(const uint4*)pa1;
  uint4 b0 = *(const uint4*)pb0, b1 = *(const uint4*)pb1;
  *(uint4*)(&As[0][l0]) = a0; *(uint4*)(&As[0][l1]) = a1;
  *(uint4*)(&Bs[0][l0]) = b0; *(uint4*)(&Bs[0][l1]) = b1;
  a0 = *(const uint4*)(pa0 + 32); a1 = *(const uint4*)(pa1 + 32);
  b0 = *(const uint4*)(pb0 + 32); b1 = *(const uint4*)(pb1 + 32);

  const int NIT = ksl / 32;
  for (int it = 0; it < NIT; ++it) {
    __syncthreads();
    int cur = it & 1;
    if (it + 1 < NIT) {
      *(uint4*)(&As[cur ^ 1][l0]) = a0; *(uint4*)(&As[cur ^ 1][l1]) = a1;
      *(uint4*)(&Bs[cur ^ 1][l0]) = b0; *(uint4*)(&Bs[cur ^ 1][l1]) = b1;
    }
    if (it + 2 < NIT) {
      a0 = *(const uint4*)(pa0 + (it + 2) * 32);
      a1 = *(const uint4*)(pa1 + (it + 2) * 32);
      b0 = *(const uint4*)(pb0 + (it + 2) * 32);
      b1 = *(const uint4*)(pb1 + (it + 2) * 32);
    }
    short8 af[4], bf[4];
#pragma unroll
    for (int i = 0; i < 4; ++i)
      af[i] = *(const short8*)(&As[cur][(wr + i * 16 + mr) * 40 + quad * 8]);
#pragma unroll
    for (int j = 0; j < 4; ++j)
      bf[j] = *(const short8*)(&Bs[cur][(wc + j * 16 + mr) * 40 + quad * 8]);
#pragma unroll
    for (int i = 0; i < 4; ++i)
#pragma unroll
      for (int j = 0; j < 4; ++j)
        acc[i][j] = __builtin_amdgcn_mfma_f32_16x16x32_bf16(af[i], bf[j],
                                                            acc[i][j], 0, 0, 0);
  }
#pragma unroll
  for (int i = 0; i < 4; ++i) {
    int crow = tm + wr + i * 16 + quad * 4;
#pragma unroll
    for (int j = 0; j < 4; ++j) {
      int ccol = tn + wc + j * 16 + mr;
#pragma unroll
      for (int r = 0; r < 4; ++r)
        C[(long)(crow + r) * P_CLS + ccol] = acc[i][j][r] * TAU_INV;
    }
  }
}

// One block per (pair,p) row: sum nkz split-K partials, logsumexp - diag.
__global__ __launch_bounds__(256)
void k_lse(const float* __restrict__ logits, float* __restrict__ lsep, int nkz) {
  __shared__ float sred[12];
  int row = blockIdx.x;  // 0 .. 3*P-1
  int p = row & (P_CLS - 1);
  int t = threadIdx.x, lane = t & 63, wv = t >> 6;
  float v0 = 0.f, v1 = 0.f;
  for (int z = 0; z < nkz; ++z) {
    const float* L = logits + ((long)z * 3 * P_CLS + row) * P_CLS;
    v0 += L[t];
    v1 += L[t + 256];
  }
  float dg = 0.f;
  if (t == p) dg = v0;
  if (t + 256 == p) dg = v1;
  float mx = xred_max(fmaxf(v0, v1));
  if (lane == 0) sred[wv] = mx;
  __syncthreads();
  mx = fmaxf(fmaxf(sred[0], sred[1]), fmaxf(sred[2], sred[3]));
  float e = expf(v0 - mx) + expf(v1 - mx);
  e = xred_sum(e);
  dg = xred_sum(dg);
  if (lane == 0) { sred[4 + wv] = e; sred[8 + wv] = dg; }
  __syncthreads();
  if (t == 0) {
    float tot = sred[4] + sred[5] + sred[6] + sred[7];
    float dgt = sred[8] + sred[9] + sred[10] + sred[11];
    lsep[row] = mx + logf(tot) - dgt;
  }
}

// Single block: reduce 1536 sn + 1536 lse values, combine to scalar loss.
__global__ __launch_bounds__(256)
void k_final(const float* __restrict__ snbuf, const float* __restrict__ lsep,
             float* __restrict__ out, float invN) {
  __shared__ float sr[8];
  int t = threadIdx.x, lane = t & 63, wv = t >> 6;
  float s = 0.f, l = 0.f;
#pragma unroll
  for (int i = 0; i < 6; ++i) {
    s += snbuf[t + 256 * i];
    l += lsep[t + 256 * i];
  }
  s = xred_sum(s);
  l = xred_sum(l);
  if (lane == 0) { sr[wv] = s; sr[4 + wv] = l; }
  __syncthreads();
  if (t == 0) {
    float sn_tot = sr[0] + sr[1] + sr[2] + sr[3];
    float lse_tot = sr[4] + sr[5] + sr[6] + sr[7];
    out[0] = 6.0f - 2.0f * invN * sn_tot + lse_tot * (1.0f / (float)P_CLS);
  }
}

extern "C" void kernel_launch(void* const* d_in, const int* in_sizes, int n_in,
                              void* d_out, int out_size, void* d_ws, size_t ws_size,
                              hipStream_t stream) {
  const float* fvp = (const float*)d_in[0];
  const float* fap = (const float*)d_in[1];
  const float* frp = (const float*)d_in[2];
  const int* label = (const int*)d_in[3];
  int N = in_sizes[3];

  char* ws = (char*)d_ws;
  float* snbuf = (float*)ws;                              // 6 KiB
  float* lsep = (float*)(ws + 8192);                      // 6 KiB
  __hip_bfloat16* cb = (__hip_bfloat16*)(ws + 65536);     // 6 MiB
  float* logits = (float*)(ws + 65536 + 3ul * P_CLS * D_DIM * 2);

  size_t base = 65536 + 3ul * P_CLS * D_DIM * 2;
  size_t per_z = 3ul * P_CLS * P_CLS * 4;
  int KZ = (ws_size >= base + 4 * per_z) ? 4 : 2;

  hipLaunchKernelGGL(k_centers, dim3(P_CLS, 3), dim3(256), 0, stream,
                     fvp, fap, frp, label, N, cb, snbuf);
  hipLaunchKernelGGL(k_gemm, dim3(16, 3, KZ), dim3(256), 0, stream, cb, logits);
  hipLaunchKernelGGL(k_lse, dim3(3 * P_CLS), dim3(256), 0, stream, logits, lsep, KZ);
  hipLaunchKernelGGL(k_final, dim3(1), dim3(256), 0, stream, snbuf, lsep,
                     (float*)d_out, 1.0f / (float)N);
}